// Round 4
// baseline (214.448 us; speedup 1.0000x reference)
//
#include <hip/hip_runtime.h>
#include <hip/hip_bf16.h>

// ---- problem constants ----
#define OUT_CH   31
#define COEF_LEN 7688           // 31*31*8
#define NPIX     16384          // 128*128
#define CHUNKS   31             // one per input channel
#define NFRG     24             // param fragments per chunk (384 padded rows)
#define NR       9              // K-steps: r = ky*3+kx; K = 9*32 (k = r*32 + ci)
#define FRAG_B   1024           // bytes per fragment per r (64 lanes x 16B)
#define CHUNK_B  (NFRG*NR*FRAG_B)         // 221184
#define BP2_B    ((size_t)CHUNKS*CHUNK_B) // 6,856,704
#define BIAS_ELE (CHUNKS*NFRG*16)         // 11904 f32
#define PART_ELE ((size_t)4*OUT_CH*NPIX)  // 2,031,616 f32
#define WS_NEED  (BP2_B + (size_t)BIAS_ELE*4 + PART_ELE*4)

// LDS layout (161,408 B total; 1 block/CU, 8 waves)
#define PBUF_B      24576                 // one r-step, all 24 frags
#define NBUF        3                     // triple buffer (1-barrier/step epochs)
#define SLAB_OFF    (NBUF*PBUF_B)         // 73728
#define SLAB_STRIDE 40                    // u16 slots: 80B row, 16B-aligned, 20-bank stagger
#define SLAB_B      (4*130*SLAB_STRIDE*2) // 41600
#define OACC_OFF    (SLAB_OFF + SLAB_B)   // 115328
#define OACC_STRIDE 33
#define OACC_B      (256*OACC_STRIDE*4)   // 33792
#define BIASL_OFF   (OACC_OFF + OACC_B)   // 149120
#define BIASL_B     (8*NFRG*16*4)         // 12288
#define LDS_BYTES   (BIASL_OFF + BIASL_B) // 161408

using f32x4 = __attribute__((ext_vector_type(4))) float;
using s16x8 = __attribute__((ext_vector_type(8))) short;

__device__ __forceinline__ unsigned short f2bf(float f) {
    unsigned int u = __float_as_uint(f);
    unsigned int r = (u + 0x7FFFu + ((u >> 16) & 1u)) >> 16;
    return (unsigned short)r;
}

// ---------------------------------------------------------------------------
// Pack gen_w/gen_b into bf16 A-fragment layout + bias table.
//  bp2[i][f][r][lane][8] bf16: MFMA A-frag for chunk i, frag f, K-step r.
//   M-row m = lane&15; k-in-step = (lane>>4)*8 + jj = conv input channel ci.
//   param identity: o = (m>>2)*8 + f/3, jslot = (f%3)*4 + (m&3)
//     jslot 0..7 = coef j, 8 = univ, 9 = res, 10..11 = zero pad
//  bias_pk[i][f][m] f32 = gb[p].
// ---------------------------------------------------------------------------
__global__ void pack_kernel(const float* __restrict__ gw, const float* __restrict__ gb,
                            unsigned short* __restrict__ bp, float* __restrict__ bias_pk) {
    const long NU = (long)CHUNKS * NFRG * NR * 64;
    long tt = (long)blockIdx.x * 256 + threadIdx.x;
    if (tt < NU) {
        int lane = (int)(tt & 63);
        long t2 = tt >> 6;
        int r = (int)(t2 % NR); t2 /= NR;
        int f = (int)(t2 % NFRG);
        int i = (int)(t2 / NFRG);
        int m = lane & 15, q8 = lane >> 4;
        int o = (m >> 2) * 8 + f / 3;
        int jslot = (f % 3) * 4 + (m & 3);
        s16x8 v;
        #pragma unroll
        for (int jj = 0; jj < 8; ++jj) {
            int ci = q8 * 8 + jj;
            float val = 0.f;
            if (ci < 31 && o < OUT_CH && jslot < 10) {
                int p;
                if (jslot < 8)       p = i * 248 + o * 8 + jslot;
                else if (jslot == 8) p = COEF_LEN + i * 31 + o;
                else                 p = COEF_LEN + 961 + i * 31 + o;
                val = gw[(long)p * 279 + ci * 9 + r];
            }
            v[jj] = (short)f2bf(val);
        }
        *reinterpret_cast<s16x8*>(bp + tt * 8) = v;
    } else if (tt < NU + BIAS_ELE) {
        long u = tt - NU;
        int m = (int)(u & 15);
        long t2 = u >> 4;
        int f = (int)(t2 % NFRG);
        int i = (int)(t2 / NFRG);
        int o = (m >> 2) * 8 + f / 3;
        int jslot = (f % 3) * 4 + (m & 3);
        float val = 0.f;
        if (o < OUT_CH && jslot < 10) {
            int p;
            if (jslot < 8)       p = i * 248 + o * 8 + jslot;
            else if (jslot == 8) p = COEF_LEN + i * 31 + o;
            else                 p = COEF_LEN + 961 + i * 31 + o;
            val = gb[p];
        }
        bias_pk[u] = val;
    }
}

__device__ __forceinline__ void stage_step(const unsigned short* __restrict__ bp2,
                                           char* smem, int bufsel, int ic, int r, int tid) {
    #pragma unroll
    for (int s = 0; s < 3; ++s) {
        int u = tid + 512 * s;                 // 1536 units of 16B = 24KB
        int f = u >> 6;
        int l = u & 63;
        const char* gsrc = (const char*)bp2 +
            ((((size_t)ic * NFRG + f) * NR + r) * 64 + l) * 16;
        char* ldst = smem + bufsel * PBUF_B + u * 16;   // wave-uniform base + lane*16
        __builtin_amdgcn_global_load_lds(
            (const __attribute__((address_space(1))) void*)gsrc,
            (__attribute__((address_space(3))) void*)ldst, 16, 0, 0);
    }
}

// ---------------------------------------------------------------------------
// Fused conv-GEMM + KAN epilogue, counted-vmcnt pipeline.
// Per step: STAGE(t+1) -> vmcnt(3) (never 0 in-loop) -> raw s_barrier ->
// ds_read A/B -> setprio(1) 48 MFMA setprio(0) [-> epilogue at r==8].
// Triple-buffered param stage; NO other vmem in the loop (bias in LDS,
// epilogue x from bf16 slab). Partials stored per chunk-group (no atomics)
// unless ws too small (use_part==0 -> atomicAdd fallback).
// ---------------------------------------------------------------------------
__global__ void __launch_bounds__(512, 1)
main_kernel(const float* __restrict__ x, const unsigned short* __restrict__ bp2,
            const float* __restrict__ bias_pk, float* __restrict__ dst, int use_part) {
    extern __shared__ char smem[];
    const int tid = threadIdx.x;
    const int bid = blockIdx.x;
    const int cg = bid & 3;
    const int pb = bid >> 2;
    const int c0 = cg * 8;
    const int c1 = (c0 + 8 < CHUNKS) ? c0 + 8 : CHUNKS;
    const int H0 = pb * 2;

    // slab: [rr 0..3][cc 0..129][slot 0..39] bf16; image row H0-1+rr, col cc-1
    unsigned short* slab = (unsigned short*)(smem + SLAB_OFF);
    for (int idx = tid; idx < 4 * 130 * 32; idx += 512) {
        int slot = idx & 31;
        int t = idx >> 5;
        int cc = t % 130;
        int rr = t / 130;
        int hh = H0 - 1 + rr, ww = cc - 1;
        float v = 0.f;
        if (slot < 31 && (unsigned)hh < 128u && (unsigned)ww < 128u)
            v = x[slot * NPIX + hh * 128 + ww];
        slab[(rr * 130 + cc) * SLAB_STRIDE + slot] = f2bf(v);
    }
    // zero output partial accumulator
    float* oaccl = (float*)(smem + OACC_OFF);
    for (int idx = tid; idx < 256 * OACC_STRIDE; idx += 512) oaccl[idx] = 0.f;
    // bias -> LDS  [chunk-local][frag][m]
    float* biasl = (float*)(smem + BIASL_OFF);
    for (int idx = tid; idx < (c1 - c0) * NFRG * 16; idx += 512)
        biasl[idx] = bias_pk[(size_t)c0 * NFRG * 16 + idx];

    // prologue: stage step 0 into buf 0; full drain once
    stage_step(bp2, smem, 0, c0, 0, tid);
    __syncthreads();

    const int lane = tid & 63;
    const int wave = tid >> 6;
    const int wm = wave >> 2;       // 0..1: frags [wm*12, wm*12+12)
    const int wn = wave & 3;        // 0..3: pixels [wn*64, wn*64+64)
    const int q = lane >> 4;
    const int pix16 = lane & 15;
    const int hloc = wn >> 1;
    const int wbase = (wn & 1) * 64 + pix16;

    int sa[4], pxl[4];
    #pragma unroll
    for (int pg = 0; pg < 4; ++pg) {
        pxl[pg] = wn * 64 + pg * 16 + pix16;
        sa[pg] = SLAB_OFF + (hloc * 130 + wbase + pg * 16) * (SLAB_STRIDE * 2) + q * 16;
    }

    int cur = 0;
    #pragma unroll 1
    for (int ic = c0; ic < c1; ++ic) {
        // acc init = bias (from LDS)
        f32x4 acc[12][4];
        const float* bl = biasl + ((ic - c0) * NFRG + wm * 12) * 16 + q * 4;
        #pragma unroll
        for (int fl = 0; fl < 12; ++fl) {
            f32x4 b = *reinterpret_cast<const f32x4*>(bl + fl * 16);
            #pragma unroll
            for (int pg = 0; pg < 4; ++pg) acc[fl][pg] = b;
        }

        #pragma unroll
        for (int r = 0; r < 9; ++r) {
            const bool last = (ic == c1 - 1) && (r == 8);
            if (!last) {
                int nic = (r < 8) ? ic : ic + 1;
                int nr  = (r < 8) ? r + 1 : 0;
                stage_step(bp2, smem, (cur == 2) ? 0 : cur + 1, nic, nr, tid);
                asm volatile("s_waitcnt vmcnt(3)" ::: "memory");
            } else {
                asm volatile("s_waitcnt vmcnt(0)" ::: "memory");
            }
            __builtin_amdgcn_s_barrier();
            __builtin_amdgcn_sched_barrier(0);

            const int roff = ((r / 3) * 130 + (r % 3)) * (SLAB_STRIDE * 2);
            s16x8 pbv[4];
            #pragma unroll
            for (int pg = 0; pg < 4; ++pg)
                pbv[pg] = *reinterpret_cast<const s16x8*>(smem + sa[pg] + roff);

            __builtin_amdgcn_s_setprio(1);
            #pragma unroll
            for (int fl = 0; fl < 12; ++fl) {
                s16x8 pa = *reinterpret_cast<const s16x8*>(
                    smem + cur * PBUF_B + (wm * 12 + fl) * FRAG_B + lane * 16);
                #pragma unroll
                for (int pg = 0; pg < 4; ++pg)
                    acc[fl][pg] = __builtin_amdgcn_mfma_f32_16x16x32_bf16(pa, pbv[pg], acc[fl][pg], 0, 0, 0);
            }
            __builtin_amdgcn_s_setprio(0);

            if (r == 8) {
                // lane-local epilogue: closed-form cubic B-spline + silu residual
                #pragma unroll
                for (int pg = 0; pg < 4; ++pg) {
                    const int scol = wbase + pg * 16;
                    unsigned short sv = *reinterpret_cast<const unsigned short*>(
                        smem + SLAB_OFF + (((hloc + 1) * 130 + scol + 1) * SLAB_STRIDE + ic) * 2);
                    float xv = __uint_as_float((unsigned)sv << 16);
                    float u5 = (xv + 1.0f) * 2.5f;
                    float cf = fminf(fmaxf(floorf(u5), 0.f), 4.f);
                    int ccb = (int)cf;
                    float t = u5 - cf;
                    float omt = 1.f - t;
                    float t2v = t * t, t3v = t2v * t;
                    float bw0 = omt * omt * omt * (1.f / 6.f);
                    float bw1 = (3.f * t3v - 6.f * t2v + 4.f) * (1.f / 6.f);
                    float bw2 = (-3.f * t3v + 3.f * t2v + 3.f * t + 1.f) * (1.f / 6.f);
                    float bw3 = t3v * (1.f / 6.f);
                    float sl = xv / (1.f + __expf(-xv));
                    float w[8];
                    #pragma unroll
                    for (int j = 0; j < 8; ++j) {
                        float wv = 0.f;
                        wv = (j == ccb)     ? bw0 : wv;
                        wv = (j == ccb + 1) ? bw1 : wv;
                        wv = (j == ccb + 2) ? bw2 : wv;
                        wv = (j == ccb + 3) ? bw3 : wv;
                        w[j] = wv;
                    }
                    float* orow = oaccl + pxl[pg] * OACC_STRIDE;
                    #pragma unroll
                    for (int t4 = 0; t4 < 4; ++t4) {
                        float sp = 0.f;
                        #pragma unroll
                        for (int j = 0; j < 8; ++j)
                            sp = fmaf(w[j], acc[3 * t4 + (j >> 2)][pg][j & 3], sp);
                        float uv = acc[3 * t4 + 2][pg][0];
                        float rv = acc[3 * t4 + 2][pg][1];
                        int o = q * 8 + wm * 4 + t4;
                        orow[o] += uv * sp + sl * rv;   // lane-private word, no race
                    }
                }
            }
            cur = (cur == 2) ? 0 : cur + 1;
        }
    }

    // finale: lane-private readback (same (pxl,o) mapping as epilogue writes)
    #pragma unroll
    for (int pg = 0; pg < 4; ++pg) {
        #pragma unroll
        for (int t4 = 0; t4 < 4; ++t4) {
            int o = q * 8 + wm * 4 + t4;
            if (o < OUT_CH) {
                float v = oaccl[pxl[pg] * OACC_STRIDE + o];
                if (use_part)
                    dst[((size_t)cg * OUT_CH + o) * NPIX + pb * 256 + pxl[pg]] = v;
                else
                    atomicAdd(dst + (size_t)o * NPIX + pb * 256 + pxl[pg], v);
            }
        }
    }
}

__global__ void reduce_kernel(const float* __restrict__ part, float* __restrict__ out) {
    int e = blockIdx.x * 256 + threadIdx.x;
    if (e < OUT_CH * NPIX) {
        const size_t s = (size_t)OUT_CH * NPIX;
        out[e] = (part[e] + part[e + s]) + (part[e + 2 * s] + part[e + 3 * s]);
    }
}

extern "C" void kernel_launch(void* const* d_in, const int* in_sizes, int n_in,
                              void* d_out, int out_size, void* d_ws, size_t ws_size,
                              hipStream_t stream) {
    const float* x  = (const float*)d_in[0];   // (1,31,128,128)
    const float* gw = (const float*)d_in[1];   // (9610,31,3,3)
    const float* gb = (const float*)d_in[2];   // (9610,)
    float* outp = (float*)d_out;               // (1,31,128,128)
    unsigned short* bpack = (unsigned short*)d_ws;
    float* bias_pk = (float*)((char*)d_ws + BP2_B);
    float* part    = (float*)((char*)d_ws + BP2_B + (size_t)BIAS_ELE * 4);

    hipFuncSetAttribute((const void*)main_kernel,
                        hipFuncAttributeMaxDynamicSharedMemorySize, LDS_BYTES);

    const long NU = (long)CHUNKS * NFRG * NR * 64;
    int pack_blocks = (int)((NU + BIAS_ELE + 255) / 256);
    pack_kernel<<<pack_blocks, 256, 0, stream>>>(gw, gb, bpack, bias_pk);

    if (ws_size >= WS_NEED) {
        main_kernel<<<256, 512, LDS_BYTES, stream>>>(x, bpack, bias_pk, part, 1);
        reduce_kernel<<<(OUT_CH * NPIX + 255) / 256, 256, 0, stream>>>(part, outp);
    } else {
        hipMemsetAsync(d_out, 0, (size_t)out_size * sizeof(float), stream);
        main_kernel<<<256, 512, LDS_BYTES, stream>>>(x, bpack, bias_pk, outp, 0);
    }
}